// Round 1
// 647.829 us; speedup vs baseline: 1.0563x; 1.0563x over previous
//
#include <hip/hip_runtime.h>

// Sliding-window bandwidth-weighted regression moments.
// B=4, H=720, W=1280, C=3, win=11 (R=5), bandwidth=0.5 -> inv_bw2=4.
// Outputs (concatenated): x/wsum, xx/wsum, xy/wsum, y/wsum, each [B,H,W,C] fp32.
//
// R3 -> R4:
//  - LSTR 75 -> 76 (rows 16B-aligned for every thread) and LDS row reads done
//    as ds_read_b128 pairs into a register row cache (924 -> 264 LDS insts
//    per thread, batched -> fewer lgkmcnt stalls, more ILP).
//  - OOB taps staged as sentinel t=1e19 (d >= 1e38 -> w = exp2(-inf) = 0
//    exactly, r staged 0) -> inner loop has NO bounds masking at all.
//  - Staging covers the full padded LSTR*LH plane so no uninitialized LDS is
//    ever loaded (second half reads cols j=14,15 and discards them).
//  - Epilogue (LDS restage + lane-contiguous float4 stores) unchanged from R3.

#define HH   720
#define WW   1280
#define BB   4
#define RAD  5
#define TX   64      // tile width  (16 threads x KX=4)
#define TY   16      // tile height (16 threads)
#define KX   4
#define LH   26      // tile rows incl. halo
#define LSTR 76      // LDS row stride (incl. halo 74 + 2 pad; mult of 4 -> 16B align)
#define PLANE (LSTR * LH)          // 1976 floats, 7904 B (16B multiple)
#define LDS_FLOATS 12288           // max(6*PLANE=11856, 4*3072 epilogue) -> 48KB

__global__ __launch_bounds__(256, 3)
void regression_kernel(const float* __restrict__ rnd,
                       const float* __restrict__ tgt,
                       float* __restrict__ out)
{
    __shared__ __align__(16) float lds[LDS_FLOATS];   // 48 KB -> 3 blocks/CU
    float* pt0 = lds;
    float* pt1 = lds + PLANE;
    float* pt2 = lds + 2 * PLANE;
    float* pr0 = lds + 3 * PLANE;
    float* pr1 = lds + 4 * PLANE;
    float* pr2 = lds + 5 * PLANE;

    const int tx = threadIdx.x;        // 0..15
    const int ty = threadIdx.y;        // 0..15
    const int tid = ty * 16 + tx;
    const int X0 = blockIdx.x * TX;
    const int Y0 = blockIdx.y * TY;
    const int b  = blockIdx.z;

    const float SENT = 1e19f;          // sentinel: d ~ 1e38 -> w underflows to 0

    // ---- stage full padded tile (76x26, sentinel for OOB) into 6 SoA planes ----
    for (int i = tid; i < PLANE; i += 256) {
        int ly = i / LSTR;
        int lx = i - ly * LSTR;
        int gy = Y0 + ly - RAD;
        int gx = X0 + lx - RAD;
        float t0 = SENT, t1 = SENT, t2 = SENT, r0 = 0.f, r1 = 0.f, r2 = 0.f;
        if ((unsigned)gy < (unsigned)HH && (unsigned)gx < (unsigned)WW) {
            int off = ((b * HH + gy) * WW + gx) * 3;
            t0 = tgt[off + 0]; t1 = tgt[off + 1]; t2 = tgt[off + 2];
            r0 = rnd[off + 0]; r1 = rnd[off + 1]; r2 = rnd[off + 2];
        }
        pt0[i] = t0; pt1[i] = t1; pt2[i] = t2;
        pr0[i] = r0; pr1[i] = r1; pr2[i] = r2;
    }
    __syncthreads();

    // ---- center guide colors for the 4-px strip (always in-bounds) ----
    float tp0[KX], tp1[KX], tp2[KX];
    {
        int s = (ty + RAD) * LSTR + tx * KX + RAD;
        #pragma unroll
        for (int k = 0; k < KX; ++k) {
            tp0[k] = pt0[s + k]; tp1[k] = pt1[s + k]; tp2[k] = pt2[s + k];
        }
    }

    float sx0[KX] = {}, sx1[KX] = {}, sx2[KX] = {};
    float sxx0[KX] = {}, sxx1[KX] = {}, sxx2[KX] = {};
    float sxy0[KX] = {}, sxy1[KX] = {}, sxy2[KX] = {};
    float sy0[KX] = {}, sy1[KX] = {}, sy2[KX] = {};
    float sw[KX] = {};

    const float CC = -5.770780163555852f;  // -(4/bw^2) * log2(e)

#define TAPK(k)                                                         \
    {                                                                   \
        float d0 = tp0[k] - t0;                                         \
        float d1 = tp1[k] - t1;                                         \
        float d2 = tp2[k] - t2;                                         \
        float d  = d0 * d0;                                             \
        d = fmaf(d1, d1, d);                                            \
        d = fmaf(d2, d2, d);                                            \
        float w = exp2f(d * CC);     /* OOB: d*CC = -inf -> w = 0 */    \
        float wt0 = w * t0, wt1 = w * t1, wt2 = w * t2;                 \
        sx0[k] += wt0;  sx1[k] += wt1;  sx2[k] += wt2;                  \
        sxx0[k] = fmaf(wt0, t0, sxx0[k]);                               \
        sxx1[k] = fmaf(wt1, t1, sxx1[k]);                               \
        sxx2[k] = fmaf(wt2, t2, sxx2[k]);                               \
        sxy0[k] = fmaf(wt0, r0, sxy0[k]);                               \
        sxy1[k] = fmaf(wt1, r1, sxy1[k]);                               \
        sxy2[k] = fmaf(wt2, r2, sxy2[k]);                               \
        sy0[k]  = fmaf(w, r0, sy0[k]);                                  \
        sy1[k]  = fmaf(w, r1, sy1[k]);                                  \
        sy2[k]  = fmaf(w, r2, sy2[k]);                                  \
        sw[k]  += w;                                                    \
    }

    #pragma unroll 1
    for (int dy = 0; dy < 11; ++dy) {
        const int rb = (ty + dy) * LSTR + tx * KX;   // 16B-aligned byte addr
        float T0[8], T1[8], T2[8], R0[8], R1[8], R2[8];

        // ---- half 0: columns j = 0..7 (2x ds_read_b128 per plane) ----
        *(float4*)&T0[0] = *(const float4*)(pt0 + rb);
        *(float4*)&T0[4] = *(const float4*)(pt0 + rb + 4);
        *(float4*)&T1[0] = *(const float4*)(pt1 + rb);
        *(float4*)&T1[4] = *(const float4*)(pt1 + rb + 4);
        *(float4*)&T2[0] = *(const float4*)(pt2 + rb);
        *(float4*)&T2[4] = *(const float4*)(pt2 + rb + 4);
        *(float4*)&R0[0] = *(const float4*)(pr0 + rb);
        *(float4*)&R0[4] = *(const float4*)(pr0 + rb + 4);
        *(float4*)&R1[0] = *(const float4*)(pr1 + rb);
        *(float4*)&R1[4] = *(const float4*)(pr1 + rb + 4);
        *(float4*)&R2[0] = *(const float4*)(pr2 + rb);
        *(float4*)&R2[4] = *(const float4*)(pr2 + rb + 4);

        #pragma unroll
        for (int j = 0; j < 8; ++j) {
            const float t0 = T0[j], t1 = T1[j], t2 = T2[j];
            const float r0 = R0[j], r1 = R1[j], r2 = R2[j];
            #pragma unroll
            for (int k = 0; k < KX; ++k)
                if (k <= j)                      // j <= 7 <= k+10 always
                    TAPK(k)
        }

        // ---- half 1: columns j = 8..13 (loads 8..15, top 2 discarded) ----
        *(float4*)&T0[0] = *(const float4*)(pt0 + rb + 8);
        *(float4*)&T0[4] = *(const float4*)(pt0 + rb + 12);
        *(float4*)&T1[0] = *(const float4*)(pt1 + rb + 8);
        *(float4*)&T1[4] = *(const float4*)(pt1 + rb + 12);
        *(float4*)&T2[0] = *(const float4*)(pt2 + rb + 8);
        *(float4*)&T2[4] = *(const float4*)(pt2 + rb + 12);
        *(float4*)&R0[0] = *(const float4*)(pr0 + rb + 8);
        *(float4*)&R0[4] = *(const float4*)(pr0 + rb + 12);
        *(float4*)&R1[0] = *(const float4*)(pr1 + rb + 8);
        *(float4*)&R1[4] = *(const float4*)(pr1 + rb + 12);
        *(float4*)&R2[0] = *(const float4*)(pr2 + rb + 8);
        *(float4*)&R2[4] = *(const float4*)(pr2 + rb + 12);

        #pragma unroll
        for (int j2 = 0; j2 < 6; ++j2) {         // j = 8 + j2
            const float t0 = T0[j2], t1 = T1[j2], t2 = T2[j2];
            const float r0 = R0[j2], r1 = R1[j2], r2 = R2[j2];
            #pragma unroll
            for (int k = 0; k < KX; ++k)
                if (k >= j2 - 2)                 // j <= k+10 ; j >= k always
                    TAPK(k)
        }
    }
#undef TAPK

    float inv[KX];
    #pragma unroll
    for (int k = 0; k < KX; ++k) inv[k] = 1.0f / sw[k];

    // ---- epilogue: stage normalized results in LDS (tile order), then
    //      cooperative lane-contiguous float4 stores ----
    __syncthreads();   // everyone done reading the planes

    float4* l4 = (float4*)lds;           // 3072 float4; chunk c at l4[c*768]
    {
        // within chunk: row (ty) major, 48 float4 per row, thread owns 3
        const int b4 = ty * 48 + tx * 3;
#define STAGE_CHUNK(a0, a1, a2, cidx)                                          \
        {                                                                      \
            float4* p = l4 + (cidx) * 768 + b4;                                \
            p[0] = make_float4(a0[0]*inv[0], a1[0]*inv[0], a2[0]*inv[0],       \
                               a0[1]*inv[1]);                                  \
            p[1] = make_float4(a1[1]*inv[1], a2[1]*inv[1], a0[2]*inv[2],       \
                               a1[2]*inv[2]);                                  \
            p[2] = make_float4(a2[2]*inv[2], a0[3]*inv[3], a1[3]*inv[3],       \
                               a2[3]*inv[3]);                                  \
        }
        STAGE_CHUNK(sx0,  sx1,  sx2,  0)
        STAGE_CHUNK(sxx0, sxx1, sxx2, 1)
        STAGE_CHUNK(sxy0, sxy1, sxy2, 2)
        STAGE_CHUNK(sy0,  sy1,  sy2,  3)
#undef STAGE_CHUNK
    }
    __syncthreads();

    const int CH = BB * HH * WW * 3;     // 11,059,200 floats per chunk
    // 3 distinct within-chunk float4 indices per thread: r = m*256 + tid
    int rr[3], cc4[3];
    #pragma unroll
    for (int m = 0; m < 3; ++m) {
        int r = m * 256 + tid;           // 0..767 (48 float4 per tile row)
        rr[m]  = r / 48;                 // tile row 0..15
        cc4[m] = r - rr[m] * 48;         // float4 col within row
    }
    #pragma unroll
    for (int i = 0; i < 12; ++i) {
        const int c = i / 3;             // chunk
        const int m = i - c * 3;
        float4 v = l4[c * 768 + m * 256 + tid];
        const int gaddr = c * CH + ((b * HH + Y0 + rr[m]) * WW + X0) * 3 + cc4[m] * 4;
        *(float4*)(out + gaddr) = v;     // consecutive lanes -> consecutive 16B
    }
}

extern "C" void kernel_launch(void* const* d_in, const int* in_sizes, int n_in,
                              void* d_out, int out_size, void* d_ws, size_t ws_size,
                              hipStream_t stream) {
    const float* rnd = (const float*)d_in[0];   // "rand"
    const float* tgt = (const float*)d_in[1];   // "target"
    float* out = (float*)d_out;

    dim3 grid(WW / TX, HH / TY, BB);   // 20 x 45 x 4 = 3600 blocks, exact tiling
    dim3 block(16, 16);
    regression_kernel<<<grid, block, 0, stream>>>(rnd, tgt, out);
}